// Round 7
// baseline (644.775 us; speedup 1.0000x reference)
//
#include <hip/hip_runtime.h>
#include <float.h>
#include <math.h>

// ---------------------------------------------------------------------------
// Round 8: fix round-5's VGPR spill (FETCH +23MB / WRITE +43MB = scratch
//          traffic; accz[2][4] live across it-loop pushed peak regs > 128).
//   bf2 is now loaded in TWO halves of 4 k-slices ([2][4] = 32 regs live,
//   was [2][8] = 64), restoring round-3's register pressure (~120 <= 128)
//   while keeping the barrier-free it-loop (wave-private GEMM3 k-partials
//   + 4-way LDS reduction per half).
//   k_stats/k_c2/k_pack/k_pack2/k_vq unchanged from round 3 (passed, 600us).
// ws (floats): stats[6144] | c2[1024]pad | @8192 z_p[65536*128]
//              | pk1/pk2/pk3 | pkc[131072 ush] | pkf[16384 ush]
// ---------------------------------------------------------------------------

typedef __attribute__((ext_vector_type(8))) short bf16x8;
typedef __attribute__((ext_vector_type(4))) float f32x4;

__device__ __forceinline__ unsigned short f2bf(float f) {
  unsigned int u = __float_as_uint(f);
  u += 0x7FFFu + ((u >> 16) & 1u);        // round-to-nearest-even
  return (unsigned short)(u >> 16);
}

__global__ __launch_bounds__(1024)
void k_stats(const float* __restrict__ x, float* __restrict__ stats) {
  __shared__ float s1[16][64];
  __shared__ float s2[16][64];
  const int v = threadIdx.x, seg = threadIdx.y, b = blockIdx.x;
  float a = 0.f, aa = 0.f;
  const float* xp = x + (b * 1024 + seg * 64) * 64 + v;
  for (int i = 0; i < 64; ++i) { const float t = xp[i * 64]; a += t; aa += t * t; }
  s1[seg][v] = a; s2[seg][v] = aa;
  __syncthreads();
  if (seg == 0) {
    float S = 0.f, SS = 0.f;
    for (int j = 0; j < 16; ++j) { S += s1[j][v]; SS += s2[j][v]; }
    const float mu  = S * (1.f / 1024.f);
    const float var = SS * (1.f / 1024.f) - mu * mu;
    const float sd  = sqrtf(var + 1e-5f);
    stats[b * 64 + v]        = mu;
    stats[2048 + b * 64 + v] = 1.f / sd;
    stats[4096 + b * 64 + v] = sd;
  }
}

__global__ __launch_bounds__(256)
void k_c2(const float* __restrict__ centroids, float* __restrict__ c2) {
  const int k = blockIdx.x * 256 + threadIdx.x;
  const float* cp = centroids + k * 128;
  float s = 0.f;
  for (int d = 0; d < 128; d += 4) {
    const float4 c = *(const float4*)(cp + d);
    s += c.x * c.x + c.y * c.y + c.z * c.z + c.w * c.w;
  }
  c2[k] = s;
}

// Pack weights into per-lane MFMA B-fragment order (16x16x32 bf16):
// frag(nt,ks): lane l, elem j  <-  W[ks*32 + (l>>4)*8 + j][nt*16 + (l&15)]
__global__ __launch_bounds__(256)
void k_pack(const float* __restrict__ fc1_w, const float* __restrict__ fcm_w,
            const float* __restrict__ fc2_w,
            unsigned short* __restrict__ pk1, unsigned short* __restrict__ pk2,
            unsigned short* __restrict__ pk3) {
  const int idx = blockIdx.x * 256 + threadIdx.x;   // 0..20479
  const int l  = idx & 63;
  const int kb = (l >> 4) * 8, nb = l & 15;
  unsigned short t[8];
  if (idx < 2048) {
    const int nt = idx >> 7, ks = (idx >> 6) & 1;
#pragma unroll
    for (int j = 0; j < 8; ++j)
      t[j] = f2bf(fc1_w[(ks * 32 + kb + j) * 256 + nt * 16 + nb]);
#pragma unroll
    for (int j = 0; j < 8; ++j) pk1[idx * 8 + j] = t[j];
  } else if (idx < 18432) {
    const int i2 = idx - 2048;
    const int nt = i2 >> 9, ks = (i2 >> 6) & 7;
#pragma unroll
    for (int j = 0; j < 8; ++j)
      t[j] = f2bf(fcm_w[(ks * 32 + kb + j) * 512 + nt * 16 + nb]);
#pragma unroll
    for (int j = 0; j < 8; ++j) pk2[i2 * 8 + j] = t[j];
  } else {
    const int i3 = idx - 18432;
    const int nt = i3 >> 10, ks = (i3 >> 6) & 15;
#pragma unroll
    for (int j = 0; j < 8; ++j)
      t[j] = f2bf(fc2_w[(ks * 32 + kb + j) * 32 + nt * 16 + nb]);
#pragma unroll
    for (int j = 0; j < 8; ++j) pk3[i3 * 8 + j] = t[j];
  }
}

// pkc: B[k=d][n=c] = centroids[c*128+d], 64 nt x 4 ks  (idx = nt*256+ks*64+l)
// pkf: B[k=din][n=dout] = fuse_w[din*128+dout], 8 nt x 4 ks
__global__ __launch_bounds__(256)
void k_pack2(const float* __restrict__ centroids, const float* __restrict__ fuse_w,
             unsigned short* __restrict__ pkc, unsigned short* __restrict__ pkf) {
  const int idx = blockIdx.x * 256 + threadIdx.x;   // 0..18431
  const int l  = idx & 63;
  const int kb = (l >> 4) * 8, nb = l & 15;
  unsigned short t[8];
  if (idx < 16384) {
    const int nt = idx >> 8;
#pragma unroll
    for (int j = 0; j < 8; ++j)
      t[j] = f2bf(centroids[(nt * 16 + nb) * 128 + ((idx >> 6) & 3) * 32 + kb + j]);
#pragma unroll
    for (int j = 0; j < 8; ++j) pkc[idx * 8 + j] = t[j];
  } else {
    const int i2 = idx - 16384;                     // 0..2047
    const int nt = i2 >> 8, ks = (i2 >> 6) & 3;
#pragma unroll
    for (int j = 0; j < 8; ++j)
      t[j] = f2bf(fuse_w[(ks * 32 + kb + j) * 128 + nt * 16 + nb]);
#pragma unroll
    for (int j = 0; j < 8; ++j) pkf[i2 * 8 + j] = t[j];
  }
}

// LDS map (64KB, 2 blocks/CU):
//   sh0 @0      bf16 [128 d][64 p]  swz: idx ^ ((row&7)<<3)   (whole kernel)
//   sh1 @16384  bf16 [64][256] swz(r&7)  | phase A: sxn@16384 red@20480
//   sh2 @49152  bf16 [64][128] swz(r&3)  (wave-private 32-col blocks)
//   P   @16384  f32 partials [4 waves][64 r][33] (reduction, after it-loop)
__global__ __launch_bounds__(256, 2)
void k_mlp(const float* __restrict__ x,
           const float* __restrict__ enc_w, const float* __restrict__ enc_b,
           const float* __restrict__ ln_w,  const float* __restrict__ ln_b,
           const float* __restrict__ fc1_b, const float* __restrict__ fcm_b,
           const float* __restrict__ fc2_b,
           const unsigned short* __restrict__ pk1,
           const unsigned short* __restrict__ pk2,
           const unsigned short* __restrict__ pk3,
           const float* __restrict__ stats, float* __restrict__ z_p) {
  __shared__ __align__(16) char smem[65536];
  unsigned short* sh0 = (unsigned short*)smem;
  unsigned short* sh1 = (unsigned short*)(smem + 16384);
  unsigned short* sh2 = (unsigned short*)(smem + 49152);
  float* sxn = (float*)(smem + 16384);
  float* red = (float*)(smem + 20480);
  float* sew = (float*)(smem + 49152);

  const int tid  = threadIdx.x;
  const int lane = tid & 63, wv = tid >> 6;
  const int l15  = lane & 15, l16 = lane >> 4;
  const int bv   = blockIdx.x, b = bv >> 6, v = bv & 63;

  // ---------------- Phase A: xn -> encode -> LN -> sh0[d][p] (bf16, swz)
  {
    const float mn = stats[bv], rs = stats[2048 + bv];
    const float* xb = x + b * 65536 + v;
    for (int i = tid; i < 1024; i += 256) sxn[i] = (xb[i * 64] - mn) * rs;
    for (int i = tid; i < 2048; i += 256) sew[i] = enc_w[i];
    __syncthreads();
    const int p = tid >> 2, qd = tid & 3;
    float xr[16];
#pragma unroll
    for (int t = 0; t < 16; ++t) xr[t] = sxn[p * 16 + t];
    float zv[32];
    float s1 = 0.f, s2 = 0.f;
#pragma unroll
    for (int dl = 0; dl < 32; ++dl) {
      const int d = qd * 32 + dl;
      float z = enc_b[d];
#pragma unroll
      for (int t = 0; t < 16; ++t) z += xr[t] * sew[t * 128 + d];
      zv[dl] = z; s1 += z; s2 += z * z;
    }
    red[p * 4 + qd] = s1; red[256 + p * 4 + qd] = s2;
    __syncthreads();
    const float S1 = red[p * 4] + red[p * 4 + 1] + red[p * 4 + 2] + red[p * 4 + 3];
    const float S2 = red[256 + p * 4] + red[256 + p * 4 + 1] +
                     red[256 + p * 4 + 2] + red[256 + p * 4 + 3];
    const float mu  = S1 * (1.f / 128.f);
    const float rsd = rsqrtf(S2 * (1.f / 128.f) - mu * mu + 1e-5f);
#pragma unroll
    for (int dl = 0; dl < 32; ++dl) {
      const int d = qd * 32 + dl;
      const float zn = (zv[dl] - mu) * rsd * ln_w[d] + ln_b[d];
      sh0[(d * 64 + p) ^ ((d & 7) << 3)] = f2bf(zn);
    }
  }
  __syncthreads();

  for (int hf = 0; hf < 2; ++hf) {
    // -------------- GEMM1: h1[64][256] = relu(h0[hf*64..][:] @ fc1 + b1)
    {
      bf16x8 bf1[4][2];
#pragma unroll
      for (int nt = 0; nt < 4; ++nt) {
        const int ntg = wv * 4 + nt;
#pragma unroll
        for (int ks = 0; ks < 2; ++ks)
          bf1[nt][ks] = *(const bf16x8*)(pk1 + (((ntg * 2 + ks) * 64 + lane) << 3));
      }
      const int swa = (l15 & 7) << 3;
      bf16x8 am[4][2];
#pragma unroll
      for (int m = 0; m < 4; ++m) {
        const int row = hf * 64 + m * 16 + l15;
#pragma unroll
        for (int ks = 0; ks < 2; ++ks)
          am[m][ks] = *(const bf16x8*)(sh0 + ((row * 64 + ks * 32 + l16 * 8) ^ swa));
      }
      f32x4 acc1[4][4];
#pragma unroll
      for (int nt = 0; nt < 4; ++nt)
#pragma unroll
        for (int m = 0; m < 4; ++m) {
          f32x4 a; a[0] = 0.f; a[1] = 0.f; a[2] = 0.f; a[3] = 0.f;
          a = __builtin_amdgcn_mfma_f32_16x16x32_bf16(am[m][0], bf1[nt][0], a, 0, 0, 0);
          a = __builtin_amdgcn_mfma_f32_16x16x32_bf16(am[m][1], bf1[nt][1], a, 0, 0, 0);
          acc1[nt][m] = a;
        }
#pragma unroll
      for (int nt = 0; nt < 4; ++nt) {
        const int n = (wv * 4 + nt) * 16 + l15;
        const float bb = fc1_b[n];
#pragma unroll
        for (int m = 0; m < 4; ++m)
#pragma unroll
          for (int j = 0; j < 4; ++j) {
            const int r = m * 16 + l16 * 4 + j;
            const float vv = acc1[nt][m][j] + bb;
            sh1[(r * 256 + n) ^ ((r & 7) << 3)] = f2bf(vv > 0.f ? vv : 0.f);
          }
      }
    }
    __syncthreads();

    // -------------- it-loop: GEMM2 chunk -> own sh2 cols -> GEMM3 k-partial
    //                (zero barriers: sh2 traffic is wave-private)
    f32x4 accz[2][4];   // [nt][mt] partial over this wave's k-blocks
#pragma unroll
    for (int nt = 0; nt < 2; ++nt)
#pragma unroll
      for (int m = 0; m < 4; ++m) {
        accz[nt][m][0] = 0.f; accz[nt][m][1] = 0.f;
        accz[nt][m][2] = 0.f; accz[nt][m][3] = 0.f;
      }

    for (int it = 0; it < 4; ++it) {
      f32x4 acc2[2][4];
#pragma unroll
      for (int nt = 0; nt < 2; ++nt)
#pragma unroll
        for (int m = 0; m < 4; ++m) {
          acc2[nt][m][0] = 0.f; acc2[nt][m][1] = 0.f;
          acc2[nt][m][2] = 0.f; acc2[nt][m][3] = 0.f;
        }
      // two half-loads of bf2 keep peak live regs ~120 (round-5's [2][8]
      // upfront load spilled at the 128-VGPR allocation)
#pragma unroll
      for (int kh = 0; kh < 2; ++kh) {
        bf16x8 bf2[2][4];
#pragma unroll
        for (int nt = 0; nt < 2; ++nt) {
          const int ntg = it * 8 + wv * 2 + nt;
#pragma unroll
          for (int ks = 0; ks < 4; ++ks)
            bf2[nt][ks] = *(const bf16x8*)(pk2 +
                            (((ntg * 8 + kh * 4 + ks) * 64 + lane) << 3));
        }
#pragma unroll
        for (int ks = 0; ks < 4; ++ks) {
          const int ksg = kh * 4 + ks;
          bf16x8 a2[4];
#pragma unroll
          for (int m = 0; m < 4; ++m) {
            const int row = m * 16 + l15;
            a2[m] = *(const bf16x8*)(sh1 +
                      ((row * 256 + ksg * 32 + l16 * 8) ^ ((row & 7) << 3)));
          }
#pragma unroll
          for (int nt = 0; nt < 2; ++nt)
#pragma unroll
            for (int m = 0; m < 4; ++m)
              acc2[nt][m] = __builtin_amdgcn_mfma_f32_16x16x32_bf16(
                  a2[m], bf2[nt][ks], acc2[nt][m], 0, 0, 0);
        }
      }
      // epilogue -> own 32-col block of sh2 (swz (r&3)<<3 stays in-block)
#pragma unroll
      for (int nt = 0; nt < 2; ++nt) {
        const float bb = fcm_b[(it * 8 + wv * 2 + nt) * 16 + l15];
        const int c = (wv * 2 + nt) * 16 + l15;
#pragma unroll
        for (int m = 0; m < 4; ++m)
#pragma unroll
          for (int j = 0; j < 4; ++j) {
            const int r = m * 16 + l16 * 4 + j;
            const float vv = acc2[nt][m][j] + bb;
            sh2[(r * 128 + c) ^ ((r & 3) << 3)] = f2bf(vv > 0.f ? vv : 0.f);
          }
      }
      // GEMM3 k-partial over own cols (global k = it*128 + wv*32 + 0..31)
      {
        bf16x8 b3[2];
#pragma unroll
        for (int nt = 0; nt < 2; ++nt)
          b3[nt] = *(const bf16x8*)(pk3 +
                     (((nt * 16 + it * 4 + wv) * 64 + lane) << 3));
#pragma unroll
        for (int mt = 0; mt < 4; ++mt) {
          const int row = mt * 16 + l15;
          const bf16x8 a3 = *(const bf16x8*)(sh2 +
                              ((row * 128 + wv * 32 + l16 * 8) ^ ((row & 3) << 3)));
#pragma unroll
          for (int nt = 0; nt < 2; ++nt)
            accz[nt][mt] = __builtin_amdgcn_mfma_f32_16x16x32_bf16(
                a3, b3[nt], accz[nt][mt], 0, 0, 0);
        }
      }
    }
    __syncthreads();   // all waves done with sh1/sh2 for this half

    // -------------- cross-wave reduction of GEMM3 partials (+bias) -> z_p
    {
      float* part = (float*)(smem + 16384) + wv * 3072;   // [64][33] per wave
#pragma unroll
      for (int nt = 0; nt < 2; ++nt) {
        const int f = nt * 16 + l15;
#pragma unroll
        for (int m = 0; m < 4; ++m)
#pragma unroll
          for (int j = 0; j < 4; ++j)
            part[(m * 16 + l16 * 4 + j) * 33 + f] = accz[nt][m][j];
      }
    }
    __syncthreads();
    {
      const float* P = (float*)(smem + 16384);
      const int f = tid >> 3, r0 = (tid & 7) * 8;
      const float bz = fc2_b[f];
      float o[8];
#pragma unroll
      for (int e = 0; e < 8; ++e) {
        const int i = (r0 + e) * 33 + f;
        o[e] = P[i] + P[3072 + i] + P[6144 + i] + P[9216 + i] + bz;
      }
      float* zp = z_p + (bv * 32 + f) * 128 + hf * 64 + r0;
      *(float4*)(zp)     = make_float4(o[0], o[1], o[2], o[3]);
      *(float4*)(zp + 4) = make_float4(o[4], o[5], o[6], o[7]);
    }
    __syncthreads();   // before next half rewrites sh1/sh2
  }
}

// Block = one (b,v): rows f=0..31, 4 waves.  (unchanged from round 3)
__global__ __launch_bounds__(256)
void k_vq(const float* __restrict__ z_p, const float* __restrict__ centroids,
          const float* __restrict__ c2g,
          const unsigned short* __restrict__ pkc,
          const unsigned short* __restrict__ pkf,
          const float* __restrict__ fuse_b,
          const float* __restrict__ fln_w,  const float* __restrict__ fln_b,
          const float* __restrict__ dec_w,  const float* __restrict__ dec_b,
          const float* __restrict__ stats,
          float* __restrict__ outputs, float* __restrict__ logits) {
  __shared__ __align__(16) char smem[23680];
  float* sdist = (float*)smem;                        // [32][132] (dist chunks)
  float* zc    = (float*)smem;                        // [32][132] (post-merge)
  unsigned int* cand = (unsigned int*)(smem + 16896); // [32][40]
  float* z2s    = (float*)(smem + 22016);             // [32]
  float* wrow   = (float*)(smem + 22144);             // [32][5]
  int*   irow   = (int*)  (smem + 22784);             // [32][5]
  float* lnstat = (float*)(smem + 23424);             // [32][2]

  const int tid  = threadIdx.x;
  const int lane = tid & 63, wv = tid >> 6;
  const int l15  = lane & 15, l16 = lane >> 4;
  const int bv   = blockIdx.x, b = bv >> 6, v = bv & 63;

  // A-frags: lane l, elem j <- z[m*16 + (l&15)][ks*32 + (l>>4)*8 + j]
  bf16x8 za[2][4];
#pragma unroll
  for (int m = 0; m < 2; ++m)
#pragma unroll
    for (int ks = 0; ks < 4; ++ks) {
      const float* zp = z_p + (bv * 32 + m * 16 + l15) * 128 + ks * 32 + l16 * 8;
      const float4 u0 = *(const float4*)zp;
      const float4 u1 = *(const float4*)(zp + 4);
      bf16x8 t;
      t[0] = (short)f2bf(u0.x); t[1] = (short)f2bf(u0.y);
      t[2] = (short)f2bf(u0.z); t[3] = (short)f2bf(u0.w);
      t[4] = (short)f2bf(u1.x); t[5] = (short)f2bf(u1.y);
      t[6] = (short)f2bf(u1.z); t[7] = (short)f2bf(u1.w);
      za[m][ks] = t;
    }

  if (tid < 32) {     // z2 in fp32 (exact, matches reference row norms)
    const float* zp = z_p + (bv * 32 + tid) * 128;
    float s = 0.f;
    for (int d = 0; d < 128; d += 4) {
      const float4 u = *(const float4*)(zp + d);
      s += u.x * u.x + u.y * u.y + u.z * u.z + u.w * u.w;
    }
    z2s[tid] = s;
  }
  __syncthreads();

  float z2r[2][4];
#pragma unroll
  for (int m = 0; m < 2; ++m)
#pragma unroll
    for (int j = 0; j < 4; ++j) z2r[m][j] = z2s[m * 16 + l16 * 4 + j];

  unsigned int d5[5];
#pragma unroll
  for (int s = 0; s < 5; ++s) d5[s] = 0xFFFFFFFFu;

  const int row8 = tid >> 3, strip = tid & 7;

  for (int cc = 0; cc < 8; ++cc) {
    bf16x8 bfc[2][4];
#pragma unroll
    for (int nt = 0; nt < 2; ++nt) {
      const int ntg = cc * 8 + wv * 2 + nt;
#pragma unroll
      for (int ks = 0; ks < 4; ++ks)
        bfc[nt][ks] = *(const bf16x8*)(pkc + (((ntg * 4 + ks) * 64 + lane) << 3));
    }
    f32x4 acc[2][2];
#pragma unroll
    for (int nt = 0; nt < 2; ++nt)
#pragma unroll
      for (int m = 0; m < 2; ++m) {
        f32x4 a; a[0] = 0.f; a[1] = 0.f; a[2] = 0.f; a[3] = 0.f;
#pragma unroll
        for (int ks = 0; ks < 4; ++ks)
          a = __builtin_amdgcn_mfma_f32_16x16x32_bf16(za[m][ks], bfc[nt][ks], a, 0, 0, 0);
        acc[nt][m] = a;
      }
    if (cc) __syncthreads();   // previous chunk's sdist reads complete
    {
      const float c2a = c2g[cc * 128 + (wv * 2) * 16 + l15];
      const float c2b = c2g[cc * 128 + (wv * 2 + 1) * 16 + l15];
#pragma unroll
      for (int nt = 0; nt < 2; ++nt) {
        const int colc = (wv * 2 + nt) * 16 + l15;
        const float cc2 = nt ? c2b : c2a;
#pragma unroll
        for (int m = 0; m < 2; ++m)
#pragma unroll
          for (int j = 0; j < 4; ++j) {
            const int r = m * 16 + l16 * 4 + j;
            sdist[r * 132 + colc] = z2r[m][j] + cc2 - 2.f * acc[nt][m][j];
          }
      }
    }
    __syncthreads();
    // ---- logits: half-wave-contiguous 512B stores
#pragma unroll
    for (int i = 0; i < 4; ++i) {
      const int row = i * 8 + wv * 2 + (lane >> 5);
      const int c4  = (lane & 31) * 4;
      const float4 dv = *(const float4*)(sdist + row * 132 + c4);
      *(float4*)(logits + (bv * 32 + row) * 1024 + cc * 128 + c4) =
          make_float4(-dv.x, -dv.y, -dv.z, -dv.w);
    }
    // ---- top5: thread owns row row8, cols strip + 8c (2-way LDS max)
    for (int c = 0; c < 16; ++c) {
      const int col = strip + 8 * c;
      const float dvv = sdist[row8 * 132 + col];
      const unsigned int key =
          (__float_as_uint(dvv) & 0xFFFFFC00u) | (unsigned)(cc * 128 + col);
      if (key < d5[4]) {
        d5[4] = key;
        unsigned int t;
        if (d5[4] < d5[3]) { t = d5[3]; d5[3] = d5[4]; d5[4] = t; }
        if (d5[3] < d5[2]) { t = d5[2]; d5[2] = d5[3]; d5[3] = t; }
        if (d5[2] < d5[1]) { t = d5[1]; d5[1] = d5[2]; d5[2] = t; }
        if (d5[1] < d5[0]) { t = d5[0]; d5[0] = d5[1]; d5[1] = t; }
      }
    }
  }

  // ---- merge 8 partial top-5 lists per row (u32 lexicographic: dist, then k)
#pragma unroll
  for (int s = 0; s < 5; ++s) cand[row8 * 40 + strip * 5 + s] = d5[s];
  __syncthreads();
  if (tid < 32) {
    unsigned int bk[5];
    for (int s = 0; s < 5; ++s) {
      unsigned int best = 0xFFFFFFFFu; int bpos = 0;
      for (int c = 0; c < 40; ++c) {
        const unsigned int u = cand[tid * 40 + c];
        if (u < best) { best = u; bpos = c; }
      }
      bk[s] = best; cand[tid * 40 + bpos] = 0xFFFFFFFFu;
    }
    float df[5];
#pragma unroll
    for (int j = 0; j < 5; ++j) df[j] = __uint_as_float(bk[j] & 0xFFFFFC00u);
    float e[5]; float sum = 0.f;
#pragma unroll
    for (int j = 0; j < 5; ++j) { e[j] = expf(df[0] - df[j]); sum += e[j]; }
    const float inv = 1.f / sum;
#pragma unroll
    for (int j = 0; j < 5; ++j) {
      wrow[tid * 5 + j] = e[j] * inv;
      irow[tid * 5 + j] = (int)(bk[j] & 1023u);
    }
  }
  __syncthreads();

  // ---- z_code = sum_j w_j * centroids[idx_j] -> zc (overwrites sdist region)
  {
    const int r = tid >> 3, d0 = (tid & 7) * 16;
    float acc[16];
#pragma unroll
    for (int dd = 0; dd < 16; ++dd) acc[dd] = 0.f;
    for (int j = 0; j < 5; ++j) {
      const float w = wrow[r * 5 + j];
      const int   k = irow[r * 5 + j];
      const float* cp = centroids + k * 128 + d0;
#pragma unroll
      for (int dd = 0; dd < 16; dd += 4) {
        const float4 cv = *(const float4*)(cp + dd);
        acc[dd]   += w * cv.x; acc[dd+1] += w * cv.y;
        acc[dd+2] += w * cv.z; acc[dd+3] += w * cv.w;
      }
    }
#pragma unroll
    for (int dd = 0; dd < 16; dd += 4)
      *(float4*)(zc + r * 132 + d0 + dd) =
          make_float4(acc[dd], acc[dd+1], acc[dd+2], acc[dd+3]);
  }

  // ---- fusion GEMM via MFMA (reuses za A-frags); compute overlaps gather
  f32x4 fac[2][2];
  {
    bf16x8 bff[2][4];
#pragma unroll
    for (int nt = 0; nt < 2; ++nt) {
      const int ntg = wv * 2 + nt;
#pragma unroll
      for (int ks = 0; ks < 4; ++ks)
        bff[nt][ks] = *(const bf16x8*)(pkf + (((ntg * 4 + ks) * 64 + lane) << 3));
    }
#pragma unroll
    for (int nt = 0; nt < 2; ++nt)
#pragma unroll
      for (int m = 0; m < 2; ++m) {
        f32x4 a; a[0] = 0.f; a[1] = 0.f; a[2] = 0.f; a[3] = 0.f;
#pragma unroll
        for (int ks = 0; ks < 4; ++ks)
          a = __builtin_amdgcn_mfma_f32_16x16x32_bf16(za[m][ks], bff[nt][ks], a, 0, 0, 0);
        fac[nt][m] = a;
      }
  }
  __syncthreads();   // gather's zc writes visible
#pragma unroll
  for (int nt = 0; nt < 2; ++nt) {
    const int colc = (wv * 2 + nt) * 16 + l15;
    const float fbv = fuse_b[colc];
#pragma unroll
    for (int m = 0; m < 2; ++m)
#pragma unroll
      for (int j = 0; j < 4; ++j) {
        const int r = m * 16 + l16 * 4 + j;
        zc[r * 132 + colc] += fmaxf(fac[nt][m][j] + fbv, 0.f);
      }
  }
  __syncthreads();

  if (tid < 32) {
    float s = 0.f, ss = 0.f;
    for (int d = 0; d < 128; ++d) { const float t = zc[tid * 132 + d]; s += t; ss += t * t; }
    const float mu  = s * (1.f / 128.f);
    const float var = ss * (1.f / 128.f) - mu * mu;
    lnstat[tid * 2]     = mu;
    lnstat[tid * 2 + 1] = rsqrtf(var + 1e-5f);
  }
  __syncthreads();

  // ---- decode (D->16) + unpatchify + RevIN denorm
  {
    const int r = tid >> 3, tt = (tid & 7) * 2;
    const float mu = lnstat[r * 2], rsd = lnstat[r * 2 + 1];
    float o0 = dec_b[tt], o1 = dec_b[tt + 1];
    for (int d = 0; d < 128; ++d) {
      const float zf = (zc[r * 132 + d] - mu) * rsd * fln_w[d] + fln_b[d];
      o0 += zf * dec_w[d * 16 + tt];
      o1 += zf * dec_w[d * 16 + tt + 1];
    }
    const float sd = stats[4096 + bv], mn = stats[bv];
    outputs[(b * 512 + r * 16 + tt) * 64 + v]     = o0 * sd + mn;
    outputs[(b * 512 + r * 16 + tt + 1) * 64 + v] = o1 * sd + mn;
  }
}

extern "C" void kernel_launch(void* const* d_in, const int* in_sizes, int n_in,
                              void* d_out, int out_size, void* d_ws, size_t ws_size,
                              hipStream_t stream) {
  const float* x      = (const float*)d_in[0];
  const float* cent   = (const float*)d_in[1];
  const float* enc_w  = (const float*)d_in[2];
  const float* enc_b  = (const float*)d_in[3];
  const float* ln_w   = (const float*)d_in[4];
  const float* ln_b   = (const float*)d_in[5];
  const float* fc1_w  = (const float*)d_in[6];
  const float* fc1_b  = (const float*)d_in[7];
  const float* fcm_w  = (const float*)d_in[8];
  const float* fcm_b  = (const float*)d_in[9];
  const float* fc2_w  = (const float*)d_in[10];
  const float* fc2_b  = (const float*)d_in[11];
  const float* fuse_w = (const float*)d_in[12];
  const float* fuse_b = (const float*)d_in[13];
  const float* fln_w  = (const float*)d_in[14];
  const float* fln_b  = (const float*)d_in[15];
  const float* dec_w  = (const float*)d_in[16];
  const float* dec_b  = (const float*)d_in[17];

  float* ws    = (float*)d_ws;
  float* stats = ws;                  // mean[2048] rstd[2048] std[2048]
  float* c2    = ws + 6144;           // [1024]
  float* z_p   = ws + 8192;           // [65536][128]
  unsigned short* pku = (unsigned short*)(ws + 8192 + 65536 * 128);
  unsigned short* pk1 = pku;           // [16384]   (32 KB)
  unsigned short* pk2 = pku + 16384;   // [131072]  (256 KB)
  unsigned short* pk3 = pku + 147456;  // [16384]   (32 KB)
  unsigned short* pkc = pku + 163840;  // [131072]  (256 KB)
  unsigned short* pkf = pku + 294912;  // [16384]   (32 KB)

  float* outputs = (float*)d_out;
  float* logits  = (float*)d_out + 32 * 512 * 64;

  k_stats<<<dim3(32), dim3(64, 16), 0, stream>>>(x, stats);
  k_c2<<<dim3(4), dim3(256), 0, stream>>>(cent, c2);
  k_pack<<<dim3(80), dim3(256), 0, stream>>>(fc1_w, fcm_w, fc2_w, pk1, pk2, pk3);
  k_pack2<<<dim3(72), dim3(256), 0, stream>>>(cent, fuse_w, pkc, pkf);
  k_mlp<<<dim3(2048), dim3(256), 0, stream>>>(x, enc_w, enc_b, ln_w, ln_b,
      fc1_b, fcm_b, fc2_b, pk1, pk2, pk3, stats, z_p);
  k_vq<<<dim3(2048), dim3(256), 0, stream>>>(z_p, cent, c2, pkc, pkf, fuse_b,
      fln_w, fln_b, dec_w, dec_b, stats, outputs, logits);
}

// Round 8
// 590.983 us; speedup vs baseline: 1.0910x; 1.0910x over previous
//
#include <hip/hip_runtime.h>
#include <float.h>
#include <math.h>

// ---------------------------------------------------------------------------
// Round 9: revert k_mlp GEMM core to the round-3 measured-good structure
//          (193us; rounds 5-7's barrier-free variant spilled ~160B/thread of
//          scratch -> FETCH/WRITE +80MB, 235us — allocator fight abandoned),
//          and cut launch overhead: 6 kernels -> 3.
//   k_prep : c2 + fc-pack + centroid/fuse-pack in ONE kernel (156 blocks).
//   k_mlp  : RevIN stats computed IN-BLOCK (k_stats eliminated, x read once);
//            then round-3 MFMA MLP unchanged; writes stats to ws for k_vq.
//   k_vq   : unchanged from round 3.
// ws (floats): stats[6144] | c2[1024]pad | @8192 z_p[65536*128]
//              | pk1/pk2/pk3 | pkc[131072 ush] | pkf[16384 ush]
// ---------------------------------------------------------------------------

typedef __attribute__((ext_vector_type(8))) short bf16x8;
typedef __attribute__((ext_vector_type(4))) float f32x4;

__device__ __forceinline__ unsigned short f2bf(float f) {
  unsigned int u = __float_as_uint(f);
  u += 0x7FFFu + ((u >> 16) & 1u);        // round-to-nearest-even
  return (unsigned short)(u >> 16);
}

// blocks 0..3: c2 | 4..83: fc1/fcm/fc2 pack | 84..155: centroids/fuse pack
__global__ __launch_bounds__(256)
void k_prep(const float* __restrict__ centroids,
            const float* __restrict__ fc1_w, const float* __restrict__ fcm_w,
            const float* __restrict__ fc2_w, const float* __restrict__ fuse_w,
            float* __restrict__ c2,
            unsigned short* __restrict__ pk1, unsigned short* __restrict__ pk2,
            unsigned short* __restrict__ pk3, unsigned short* __restrict__ pkc,
            unsigned short* __restrict__ pkf) {
  const int blk = blockIdx.x, tid = threadIdx.x;
  if (blk < 4) {
    const int k = blk * 256 + tid;
    const float* cp = centroids + k * 128;
    float s = 0.f;
    for (int d = 0; d < 128; d += 4) {
      const float4 c = *(const float4*)(cp + d);
      s += c.x * c.x + c.y * c.y + c.z * c.z + c.w * c.w;
    }
    c2[k] = s;
    return;
  }
  // MFMA B-frag order (16x16x32 bf16):
  // frag(nt,ks): lane l, elem j <- W[ks*32 + (l>>4)*8 + j][nt*16 + (l&15)]
  const int l  = tid & 63;
  const int kb = ((l >> 4) & 3) * 8, nb = l & 15;
  unsigned short t[8];
  if (blk < 84) {
    const int idx = (blk - 4) * 256 + tid;          // 0..20479
    if (idx < 2048) {
      const int nt = idx >> 7, ks = (idx >> 6) & 1;
#pragma unroll
      for (int j = 0; j < 8; ++j)
        t[j] = f2bf(fc1_w[(ks * 32 + kb + j) * 256 + nt * 16 + nb]);
#pragma unroll
      for (int j = 0; j < 8; ++j) pk1[idx * 8 + j] = t[j];
    } else if (idx < 18432) {
      const int i2 = idx - 2048;
      const int nt = i2 >> 9, ks = (i2 >> 6) & 7;
#pragma unroll
      for (int j = 0; j < 8; ++j)
        t[j] = f2bf(fcm_w[(ks * 32 + kb + j) * 512 + nt * 16 + nb]);
#pragma unroll
      for (int j = 0; j < 8; ++j) pk2[i2 * 8 + j] = t[j];
    } else {
      const int i3 = idx - 18432;
      const int nt = i3 >> 10, ks = (i3 >> 6) & 15;
#pragma unroll
      for (int j = 0; j < 8; ++j)
        t[j] = f2bf(fc2_w[(ks * 32 + kb + j) * 32 + nt * 16 + nb]);
#pragma unroll
      for (int j = 0; j < 8; ++j) pk3[i3 * 8 + j] = t[j];
    }
  } else {
    const int idx = (blk - 84) * 256 + tid;         // 0..18431
    if (idx < 16384) {
      const int nt = idx >> 8;
#pragma unroll
      for (int j = 0; j < 8; ++j)
        t[j] = f2bf(centroids[(nt * 16 + nb) * 128 + ((idx >> 6) & 3) * 32 + kb + j]);
#pragma unroll
      for (int j = 0; j < 8; ++j) pkc[idx * 8 + j] = t[j];
    } else {
      const int i2 = idx - 16384;                   // 0..2047
      const int nt = i2 >> 8, ks = (i2 >> 6) & 3;
#pragma unroll
      for (int j = 0; j < 8; ++j)
        t[j] = f2bf(fuse_w[(ks * 32 + kb + j) * 128 + nt * 16 + nb]);
#pragma unroll
      for (int j = 0; j < 8; ++j) pkf[i2 * 8 + j] = t[j];
    }
  }
}

// LDS map (64KB, 2 blocks/CU) — round-3 layout:
//   sh0 @0      bf16 [128 d][64 p]  swz: idx ^ ((row&7)<<3)   (whole kernel)
//   sh1 @16384  bf16 [64][256] swz  (per half) | phase A: sxn@16384 red@20480
//   sh2 @49152  bf16 [64][128] swz  (per GEMM2 chunk) | phase A: sew@49152
__global__ __launch_bounds__(256, 2)
void k_mlp(const float* __restrict__ x,
           const float* __restrict__ enc_w, const float* __restrict__ enc_b,
           const float* __restrict__ ln_w,  const float* __restrict__ ln_b,
           const float* __restrict__ fc1_b, const float* __restrict__ fcm_b,
           const float* __restrict__ fc2_b,
           const unsigned short* __restrict__ pk1,
           const unsigned short* __restrict__ pk2,
           const unsigned short* __restrict__ pk3,
           float* __restrict__ stats, float* __restrict__ z_p) {
  __shared__ __align__(16) char smem[65536];
  unsigned short* sh0 = (unsigned short*)smem;
  unsigned short* sh1 = (unsigned short*)(smem + 16384);
  unsigned short* sh2 = (unsigned short*)(smem + 49152);
  float* sxn = (float*)(smem + 16384);
  float* red = (float*)(smem + 20480);
  float* sew = (float*)(smem + 49152);

  const int tid  = threadIdx.x;
  const int lane = tid & 63, wv = tid >> 6;
  const int l15  = lane & 15, l16 = lane >> 4;
  const int bv   = blockIdx.x, b = bv >> 6, v = bv & 63;

  // ---------------- Phase A0: in-block RevIN stats (k_stats fused)
  {
    const float* xb = x + b * 65536 + v;
    float s = 0.f, ss = 0.f;
    for (int i = tid; i < 1024; i += 256) {
      const float t = xb[i * 64];
      sxn[i] = t; s += t; ss += t * t;
    }
    red[tid] = s; red[256 + tid] = ss;
    for (int i = tid; i < 2048; i += 256) sew[i] = enc_w[i];
    __syncthreads();
    if (tid < 64) {
      const float a  = red[tid] + red[tid + 64] + red[tid + 128] + red[tid + 192];
      const float a2 = red[256 + tid] + red[320 + tid] + red[384 + tid] + red[448 + tid];
      red[tid] = a; red[256 + tid] = a2;
    }
    __syncthreads();
    if (tid == 0) {
      float S = 0.f, SS = 0.f;
      for (int i = 0; i < 64; ++i) { S += red[i]; SS += red[256 + i]; }
      const float mu  = S * (1.f / 1024.f);
      const float var = SS * (1.f / 1024.f) - mu * mu;
      const float sd  = sqrtf(var + 1e-5f);
      red[512] = mu; red[513] = 1.f / sd;
      stats[bv] = mu; stats[2048 + bv] = 1.f / sd; stats[4096 + bv] = sd;
    }
    __syncthreads();
  }
  const float mn = red[512], rs = red[513];
  __syncthreads();   // all threads have read red[512/513] before LN reuses red

  // ---------------- Phase A: xn -> encode -> LN -> sh0[d][p] (bf16, swz)
  {
    const int p = tid >> 2, qd = tid & 3;
    float xr[16];
#pragma unroll
    for (int t = 0; t < 16; ++t) xr[t] = (sxn[p * 16 + t] - mn) * rs;
    float zv[32];
    float s1 = 0.f, s2 = 0.f;
#pragma unroll
    for (int dl = 0; dl < 32; ++dl) {
      const int d = qd * 32 + dl;
      float z = enc_b[d];
#pragma unroll
      for (int t = 0; t < 16; ++t) z += xr[t] * sew[t * 128 + d];
      zv[dl] = z; s1 += z; s2 += z * z;
    }
    red[p * 4 + qd] = s1; red[256 + p * 4 + qd] = s2;
    __syncthreads();
    const float S1 = red[p * 4] + red[p * 4 + 1] + red[p * 4 + 2] + red[p * 4 + 3];
    const float S2 = red[256 + p * 4] + red[256 + p * 4 + 1] +
                     red[256 + p * 4 + 2] + red[256 + p * 4 + 3];
    const float mu  = S1 * (1.f / 128.f);
    const float rsd = rsqrtf(S2 * (1.f / 128.f) - mu * mu + 1e-5f);
#pragma unroll
    for (int dl = 0; dl < 32; ++dl) {
      const int d = qd * 32 + dl;
      const float zn = (zv[dl] - mu) * rsd * ln_w[d] + ln_b[d];
      sh0[(d * 64 + p) ^ ((d & 7) << 3)] = f2bf(zn);
    }
  }
  __syncthreads();

  for (int hf = 0; hf < 2; ++hf) {
    // -------------- GEMM1: h1[64][256] = relu(h0[hf*64..][:] @ fc1 + b1)
    {
      bf16x8 bf1[4][2];
#pragma unroll
      for (int nt = 0; nt < 4; ++nt) {
        const int ntg = wv * 4 + nt;
#pragma unroll
        for (int ks = 0; ks < 2; ++ks)
          bf1[nt][ks] = *(const bf16x8*)(pk1 + (((ntg * 2 + ks) * 64 + lane) << 3));
      }
      const int swa = (l15 & 7) << 3;
      bf16x8 am[4][2];
#pragma unroll
      for (int m = 0; m < 4; ++m) {
        const int row = hf * 64 + m * 16 + l15;
#pragma unroll
        for (int ks = 0; ks < 2; ++ks)
          am[m][ks] = *(const bf16x8*)(sh0 + ((row * 64 + ks * 32 + l16 * 8) ^ swa));
      }
      f32x4 acc1[4][4];
#pragma unroll
      for (int nt = 0; nt < 4; ++nt)
#pragma unroll
        for (int m = 0; m < 4; ++m) {
          f32x4 a; a[0] = 0.f; a[1] = 0.f; a[2] = 0.f; a[3] = 0.f;
          a = __builtin_amdgcn_mfma_f32_16x16x32_bf16(am[m][0], bf1[nt][0], a, 0, 0, 0);
          a = __builtin_amdgcn_mfma_f32_16x16x32_bf16(am[m][1], bf1[nt][1], a, 0, 0, 0);
          acc1[nt][m] = a;
        }
#pragma unroll
      for (int nt = 0; nt < 4; ++nt) {
        const int n = (wv * 4 + nt) * 16 + l15;
        const float bb = fc1_b[n];
#pragma unroll
        for (int m = 0; m < 4; ++m)
#pragma unroll
          for (int j = 0; j < 4; ++j) {
            const int r = m * 16 + l16 * 4 + j;
            const float vv = acc1[nt][m][j] + bb;
            sh1[(r * 256 + n) ^ ((r & 7) << 3)] = f2bf(vv > 0.f ? vv : 0.f);
          }
      }
    }
    __syncthreads();

    // -------------- GEMM2 (N=512 in 4 chunks of 128) + GEMM3 accumulate
    f32x4 accz[2];
#pragma unroll
    for (int nt = 0; nt < 2; ++nt) {
      const float bz = fc2_b[nt * 16 + l15];
      accz[nt][0] = bz; accz[nt][1] = bz; accz[nt][2] = bz; accz[nt][3] = bz;
    }

    for (int it = 0; it < 4; ++it) {
      bf16x8 bf2[2][8];
#pragma unroll
      for (int nt = 0; nt < 2; ++nt) {
        const int ntg = it * 8 + wv * 2 + nt;
#pragma unroll
        for (int ks = 0; ks < 8; ++ks)
          bf2[nt][ks] = *(const bf16x8*)(pk2 + (((ntg * 8 + ks) * 64 + lane) << 3));
      }
      f32x4 acc2[2][4];
#pragma unroll
      for (int nt = 0; nt < 2; ++nt)
#pragma unroll
        for (int m = 0; m < 4; ++m) {
          acc2[nt][m][0] = 0.f; acc2[nt][m][1] = 0.f;
          acc2[nt][m][2] = 0.f; acc2[nt][m][3] = 0.f;
        }
#pragma unroll
      for (int ks = 0; ks < 8; ++ks) {
        bf16x8 a2[4];
#pragma unroll
        for (int m = 0; m < 4; ++m) {
          const int row = m * 16 + l15;
          a2[m] = *(const bf16x8*)(sh1 +
                    ((row * 256 + ks * 32 + l16 * 8) ^ ((row & 7) << 3)));
        }
#pragma unroll
        for (int nt = 0; nt < 2; ++nt)
#pragma unroll
          for (int m = 0; m < 4; ++m)
            acc2[nt][m] = __builtin_amdgcn_mfma_f32_16x16x32_bf16(
                a2[m], bf2[nt][ks], acc2[nt][m], 0, 0, 0);
      }
#pragma unroll
      for (int nt = 0; nt < 2; ++nt) {
        const float bb = fcm_b[(it * 8 + wv * 2 + nt) * 16 + l15];
        const int c = (wv * 2 + nt) * 16 + l15;
#pragma unroll
        for (int m = 0; m < 4; ++m)
#pragma unroll
          for (int j = 0; j < 4; ++j) {
            const int r = m * 16 + l16 * 4 + j;
            const float vv = acc2[nt][m][j] + bb;
            sh2[(r * 128 + c) ^ ((r & 7) << 3)] = f2bf(vv > 0.f ? vv : 0.f);
          }
      }
      __syncthreads();
      {
        const int row = wv * 16 + l15;
        const int sw  = (row & 7) << 3;
        bf16x8 b3[2][4];
#pragma unroll
        for (int nt = 0; nt < 2; ++nt)
#pragma unroll
          for (int ks = 0; ks < 4; ++ks)
            b3[nt][ks] = *(const bf16x8*)(pk3 +
                           (((nt * 16 + it * 4 + ks) * 64 + lane) << 3));
#pragma unroll
        for (int ks = 0; ks < 4; ++ks) {
          const bf16x8 a3 = *(const bf16x8*)(sh2 +
                              ((row * 128 + ks * 32 + l16 * 8) ^ sw));
#pragma unroll
          for (int nt = 0; nt < 2; ++nt)
            accz[nt] = __builtin_amdgcn_mfma_f32_16x16x32_bf16(
                a3, b3[nt][ks], accz[nt], 0, 0, 0);
        }
      }
      __syncthreads();
    }

    // -------------- store z_p half: rows d, cols f -> z_p[(bv,f),d]
    {
      const int d0 = hf * 64 + wv * 16 + l16 * 4;
#pragma unroll
      for (int nt = 0; nt < 2; ++nt) {
        const int f = nt * 16 + l15;
        *(float4*)(z_p + (bv * 32 + f) * 128 + d0) =
            make_float4(accz[nt][0], accz[nt][1], accz[nt][2], accz[nt][3]);
      }
    }
  }
}

// Block = one (b,v): rows f=0..31, 4 waves.  (unchanged from round 3)
__global__ __launch_bounds__(256)
void k_vq(const float* __restrict__ z_p, const float* __restrict__ centroids,
          const float* __restrict__ c2g,
          const unsigned short* __restrict__ pkc,
          const unsigned short* __restrict__ pkf,
          const float* __restrict__ fuse_b,
          const float* __restrict__ fln_w,  const float* __restrict__ fln_b,
          const float* __restrict__ dec_w,  const float* __restrict__ dec_b,
          const float* __restrict__ stats,
          float* __restrict__ outputs, float* __restrict__ logits) {
  __shared__ __align__(16) char smem[23680];
  float* sdist = (float*)smem;                        // [32][132] (dist chunks)
  float* zc    = (float*)smem;                        // [32][132] (post-merge)
  unsigned int* cand = (unsigned int*)(smem + 16896); // [32][40]
  float* z2s    = (float*)(smem + 22016);             // [32]
  float* wrow   = (float*)(smem + 22144);             // [32][5]
  int*   irow   = (int*)  (smem + 22784);             // [32][5]
  float* lnstat = (float*)(smem + 23424);             // [32][2]

  const int tid  = threadIdx.x;
  const int lane = tid & 63, wv = tid >> 6;
  const int l15  = lane & 15, l16 = lane >> 4;
  const int bv   = blockIdx.x, b = bv >> 6, v = bv & 63;

  // A-frags: lane l, elem j <- z[m*16 + (l&15)][ks*32 + (l>>4)*8 + j]
  bf16x8 za[2][4];
#pragma unroll
  for (int m = 0; m < 2; ++m)
#pragma unroll
    for (int ks = 0; ks < 4; ++ks) {
      const float* zp = z_p + (bv * 32 + m * 16 + l15) * 128 + ks * 32 + l16 * 8;
      const float4 u0 = *(const float4*)zp;
      const float4 u1 = *(const float4*)(zp + 4);
      bf16x8 t;
      t[0] = (short)f2bf(u0.x); t[1] = (short)f2bf(u0.y);
      t[2] = (short)f2bf(u0.z); t[3] = (short)f2bf(u0.w);
      t[4] = (short)f2bf(u1.x); t[5] = (short)f2bf(u1.y);
      t[6] = (short)f2bf(u1.z); t[7] = (short)f2bf(u1.w);
      za[m][ks] = t;
    }

  if (tid < 32) {     // z2 in fp32 (exact, matches reference row norms)
    const float* zp = z_p + (bv * 32 + tid) * 128;
    float s = 0.f;
    for (int d = 0; d < 128; d += 4) {
      const float4 u = *(const float4*)(zp + d);
      s += u.x * u.x + u.y * u.y + u.z * u.z + u.w * u.w;
    }
    z2s[tid] = s;
  }
  __syncthreads();

  float z2r[2][4];
#pragma unroll
  for (int m = 0; m < 2; ++m)
#pragma unroll
    for (int j = 0; j < 4; ++j) z2r[m][j] = z2s[m * 16 + l16 * 4 + j];

  unsigned int d5[5];
#pragma unroll
  for (int s = 0; s < 5; ++s) d5[s] = 0xFFFFFFFFu;

  const int row8 = tid >> 3, strip = tid & 7;

  for (int cc = 0; cc < 8; ++cc) {
    bf16x8 bfc[2][4];
#pragma unroll
    for (int nt = 0; nt < 2; ++nt) {
      const int ntg = cc * 8 + wv * 2 + nt;
#pragma unroll
      for (int ks = 0; ks < 4; ++ks)
        bfc[nt][ks] = *(const bf16x8*)(pkc + (((ntg * 4 + ks) * 64 + lane) << 3));
    }
    f32x4 acc[2][2];
#pragma unroll
    for (int nt = 0; nt < 2; ++nt)
#pragma unroll
      for (int m = 0; m < 2; ++m) {
        f32x4 a; a[0] = 0.f; a[1] = 0.f; a[2] = 0.f; a[3] = 0.f;
#pragma unroll
        for (int ks = 0; ks < 4; ++ks)
          a = __builtin_amdgcn_mfma_f32_16x16x32_bf16(za[m][ks], bfc[nt][ks], a, 0, 0, 0);
        acc[nt][m] = a;
      }
    if (cc) __syncthreads();   // previous chunk's sdist reads complete
    {
      const float c2a = c2g[cc * 128 + (wv * 2) * 16 + l15];
      const float c2b = c2g[cc * 128 + (wv * 2 + 1) * 16 + l15];
#pragma unroll
      for (int nt = 0; nt < 2; ++nt) {
        const int colc = (wv * 2 + nt) * 16 + l15;
        const float cc2 = nt ? c2b : c2a;
#pragma unroll
        for (int m = 0; m < 2; ++m)
#pragma unroll
          for (int j = 0; j < 4; ++j) {
            const int r = m * 16 + l16 * 4 + j;
            sdist[r * 132 + colc] = z2r[m][j] + cc2 - 2.f * acc[nt][m][j];
          }
      }
    }
    __syncthreads();
    // ---- logits: half-wave-contiguous 512B stores
#pragma unroll
    for (int i = 0; i < 4; ++i) {
      const int row = i * 8 + wv * 2 + (lane >> 5);
      const int c4  = (lane & 31) * 4;
      const float4 dv = *(const float4*)(sdist + row * 132 + c4);
      *(float4*)(logits + (bv * 32 + row) * 1024 + cc * 128 + c4) =
          make_float4(-dv.x, -dv.y, -dv.z, -dv.w);
    }
    // ---- top5: thread owns row row8, cols strip + 8c (2-way LDS max)
    for (int c = 0; c < 16; ++c) {
      const int col = strip + 8 * c;
      const float dvv = sdist[row8 * 132 + col];
      const unsigned int key =
          (__float_as_uint(dvv) & 0xFFFFFC00u) | (unsigned)(cc * 128 + col);
      if (key < d5[4]) {
        d5[4] = key;
        unsigned int t;
        if (d5[4] < d5[3]) { t = d5[3]; d5[3] = d5[4]; d5[4] = t; }
        if (d5[3] < d5[2]) { t = d5[2]; d5[2] = d5[3]; d5[3] = t; }
        if (d5[2] < d5[1]) { t = d5[1]; d5[1] = d5[2]; d5[2] = t; }
        if (d5[1] < d5[0]) { t = d5[0]; d5[0] = d5[1]; d5[1] = t; }
      }
    }
  }

  // ---- merge 8 partial top-5 lists per row (u32 lexicographic: dist, then k)
#pragma unroll
  for (int s = 0; s < 5; ++s) cand[row8 * 40 + strip * 5 + s] = d5[s];
  __syncthreads();
  if (tid < 32) {
    unsigned int bk[5];
    for (int s = 0; s < 5; ++s) {
      unsigned int best = 0xFFFFFFFFu; int bpos = 0;
      for (int c = 0; c < 40; ++c) {
        const unsigned int u = cand[tid * 40 + c];
        if (u < best) { best = u; bpos = c; }
      }
      bk[s] = best; cand[tid * 40 + bpos] = 0xFFFFFFFFu;
    }
    float df[5];
#pragma unroll
    for (int j = 0; j < 5; ++j) df[j] = __uint_as_float(bk[j] & 0xFFFFFC00u);
    float e[5]; float sum = 0.f;
#pragma unroll
    for (int j = 0; j < 5; ++j) { e[j] = expf(df[0] - df[j]); sum += e[j]; }
    const float inv = 1.f / sum;
#pragma unroll
    for (int j = 0; j < 5; ++j) {
      wrow[tid * 5 + j] = e[j] * inv;
      irow[tid * 5 + j] = (int)(bk[j] & 1023u);
    }
  }
  __syncthreads();

  // ---- z_code = sum_j w_j * centroids[idx_j] -> zc (overwrites sdist region)
  {
    const int r = tid >> 3, d0 = (tid & 7) * 16;
    float acc[16];
#pragma unroll
    for (int dd = 0; dd < 16; ++dd) acc[dd] = 0.f;
    for (int j = 0; j < 5; ++j) {
      const float w = wrow[r * 5 + j];
      const int   k = irow[r * 5 + j];
      const float* cp = centroids + k * 128 + d0;
#pragma unroll
      for (int dd = 0; dd < 16; dd += 4) {
        const float4 cv = *(const float4*)(cp + dd);
        acc[dd]   += w * cv.x; acc[dd+1] += w * cv.y;
        acc[dd+2] += w * cv.z; acc[dd+3] += w * cv.w;
      }
    }
#pragma unroll
    for (int dd = 0; dd < 16; dd += 4)
      *(float4*)(zc + r * 132 + d0 + dd) =
          make_float4(acc[dd], acc[dd+1], acc[dd+2], acc[dd+3]);
  }

  // ---- fusion GEMM via MFMA (reuses za A-frags); compute overlaps gather
  f32x4 fac[2][2];
  {
    bf16x8 bff[2][4];
#pragma unroll
    for (int nt = 0; nt < 2; ++nt) {
      const int ntg = wv * 2 + nt;
#pragma unroll
      for (int ks = 0; ks < 4; ++ks)
        bff[nt][ks] = *(const bf16x8*)(pkf + (((ntg * 4 + ks) * 64 + lane) << 3));
    }
#pragma unroll
    for (int nt = 0; nt < 2; ++nt)
#pragma unroll
      for (int m = 0; m < 2; ++m) {
        f32x4 a; a[0] = 0.f; a[1] = 0.f; a[2] = 0.f; a[3] = 0.f;
#pragma unroll
        for (int ks = 0; ks < 4; ++ks)
          a = __builtin_amdgcn_mfma_f32_16x16x32_bf16(za[m][ks], bff[nt][ks], a, 0, 0, 0);
        fac[nt][m] = a;
      }
  }
  __syncthreads();   // gather's zc writes visible
#pragma unroll
  for (int nt = 0; nt < 2; ++nt) {
    const int colc = (wv * 2 + nt) * 16 + l15;
    const float fbv = fuse_b[colc];
#pragma unroll
    for (int m = 0; m < 2; ++m)
#pragma unroll
      for (int j = 0; j < 4; ++j) {
        const int r = m * 16 + l16 * 4 + j;
        zc[r * 132 + colc] += fmaxf(fac[nt][m][j] + fbv, 0.f);
      }
  }
  __syncthreads();

  if (tid < 32) {
    float s = 0.f, ss = 0.f;
    for (int d = 0; d < 128; ++d) { const float t = zc[tid * 132 + d]; s += t; ss += t * t; }
    const float mu  = s * (1.f / 128.f);
    const float var = ss * (1.f / 128.f) - mu * mu;
    lnstat[tid * 2]     = mu;
    lnstat[tid * 2 + 1] = rsqrtf(var + 1e-5f);
  }
  __syncthreads();

  // ---- decode (D->16) + unpatchify + RevIN denorm
  {
    const int r = tid >> 3, tt = (tid & 7) * 2;
    const float mu = lnstat[r * 2], rsd = lnstat[r * 2 + 1];
    float o0 = dec_b[tt], o1 = dec_b[tt + 1];
    for (int d = 0; d < 128; ++d) {
      const float zf = (zc[r * 132 + d] - mu) * rsd * fln_w[d] + fln_b[d];
      o0 += zf * dec_w[d * 16 + tt];
      o1 += zf * dec_w[d * 16 + tt + 1];
    }
    const float sd = stats[4096 + bv], mn = stats[bv];
    outputs[(b * 512 + r * 16 + tt) * 64 + v]     = o0 * sd + mn;
    outputs[(b * 512 + r * 16 + tt + 1) * 64 + v] = o1 * sd + mn;
  }
}

extern "C" void kernel_launch(void* const* d_in, const int* in_sizes, int n_in,
                              void* d_out, int out_size, void* d_ws, size_t ws_size,
                              hipStream_t stream) {
  const float* x      = (const float*)d_in[0];
  const float* cent   = (const float*)d_in[1];
  const float* enc_w  = (const float*)d_in[2];
  const float* enc_b  = (const float*)d_in[3];
  const float* ln_w   = (const float*)d_in[4];
  const float* ln_b   = (const float*)d_in[5];
  const float* fc1_w  = (const float*)d_in[6];
  const float* fc1_b  = (const float*)d_in[7];
  const float* fcm_w  = (const float*)d_in[8];
  const float* fcm_b  = (const float*)d_in[9];
  const float* fc2_w  = (const float*)d_in[10];
  const float* fc2_b  = (const float*)d_in[11];
  const float* fuse_w = (const float*)d_in[12];
  const float* fuse_b = (const float*)d_in[13];
  const float* fln_w  = (const float*)d_in[14];
  const float* fln_b  = (const float*)d_in[15];
  const float* dec_w  = (const float*)d_in[16];
  const float* dec_b  = (const float*)d_in[17];

  float* ws    = (float*)d_ws;
  float* stats = ws;                  // mean[2048] rstd[2048] std[2048]
  float* c2    = ws + 6144;           // [1024]
  float* z_p   = ws + 8192;           // [65536][128]
  unsigned short* pku = (unsigned short*)(ws + 8192 + 65536 * 128);
  unsigned short* pk1 = pku;           // [16384]   (32 KB)
  unsigned short* pk2 = pku + 16384;   // [131072]  (256 KB)
  unsigned short* pk3 = pku + 147456;  // [16384]   (32 KB)
  unsigned short* pkc = pku + 163840;  // [131072]  (256 KB)
  unsigned short* pkf = pku + 294912;  // [16384]   (32 KB)

  float* outputs = (float*)d_out;
  float* logits  = (float*)d_out + 32 * 512 * 64;

  k_prep<<<dim3(156), dim3(256), 0, stream>>>(cent, fc1_w, fcm_w, fc2_w, fuse_w,
      c2, pk1, pk2, pk3, pkc, pkf);
  k_mlp<<<dim3(2048), dim3(256), 0, stream>>>(x, enc_w, enc_b, ln_w, ln_b,
      fc1_b, fcm_b, fc2_b, pk1, pk2, pk3, stats, z_p);
  k_vq<<<dim3(2048), dim3(256), 0, stream>>>(z_p, cent, c2, pkc, pkf, fuse_b,
      fln_w, fln_b, dec_w, dec_b, stats, outputs, logits);
}